// Round 6
// baseline (312.402 us; speedup 1.0000x reference)
//
#include <hip/hip_runtime.h>
#include <hip/hip_fp16.h>
#include <math.h>

// ---------------- workspace layout (float offsets) ----------------
// LUT buffers are written AFTER the conv chain finishes -> overlap dead Y0/Y1.
constexpr size_t OFF_Y0    = 0;         // 8*16*128*128 = 2097152
constexpr size_t OFF_Y1    = 2097152;   // 8*32*64*64   = 1048576
constexpr size_t OFF_Y2    = 3145728;   // 8*64*32*32   = 524288
constexpr size_t OFF_Y3    = 3670016;   // 8*128*16*16  = 262144 (ends 3932160)
constexpr size_t OFF_LUTCF = 0;         // fp32 compact LUT: 8*35937*4 = 1149984
constexpr size_t OFF_LUTQ  = 1149984;   // quantized quad LUT: 8*35937*4 = 1149984 (ends 2299968)
constexpr size_t OFF_T     = 4599936;   // 300*1089 = 326700 (ends 4926636)
constexpr size_t OFF_STATB = 4926640;
constexpr size_t OFF_STAT0 = OFF_STATB + 0;     // 8*16*2  = 256
constexpr size_t OFF_STAT1 = OFF_STATB + 256;   // 8*32*2  = 512
constexpr size_t OFF_STAT2 = OFF_STATB + 768;   // 8*64*2  = 1024
constexpr size_t OFF_STAT3 = OFF_STATB + 1792;  // 8*128*2 = 2048
constexpr size_t OFF_FEATS = OFF_STATB + 3840;  // 8*128   = 1024
constexpr size_t OFF_WGT   = OFF_STATB + 4864;  // 8*20 -> 256

__global__ __launch_bounds__(256) void zero_k(float* __restrict__ p, int n) {
  int i = blockIdx.x*256 + threadIdx.x;
  if (i < n) p[i] = 0.f;
}

// ---------------- unified tiled conv: stride-2 3x3 + lrelu (+stats / +mean) ----------------
template<int CIN, int COUT, int HIN, int WIN, int TH, int OCG, int PX, int OCT,
         int BLK, int MODE, int NPXPREV>
__global__ __launch_bounds__(BLK, 2) void conv_tile(
    const float* __restrict__ xin, const float* __restrict__ wgt,
    const float* __restrict__ bias, const float* __restrict__ stat_in,
    const float* __restrict__ gam, const float* __restrict__ bet,
    float* __restrict__ yout, float* __restrict__ stat_out)
{
  constexpr int HOUT = HIN/2, WOUT = WIN/2;
  constexpr int SEG  = WOUT + 4;
  constexpr int XROW = 2*SEG;
  constexpr int XPI  = (2*TH+1)*XROW;
  constexpr int NT   = HOUT/TH;
  constexpr int NSTRIP_B = TH*WOUT/PX;
  constexpr int GPT  = OCG/OCT;
  static_assert(BLK == NSTRIP_B*GPT, "thread mapping mismatch");
  constexpr int R = NSTRIP_B < 64 ? NSTRIP_B : 64;

  __shared__ __align__(16) float xs[CIN*XPI];
  __shared__ float s_sc[CIN], s_sf[CIN];

  const int tid = threadIdx.x;
  const int lin = blockIdx.x;
  const int b = lin & 7;
  const int r2 = lin >> 3;
  const int tile = r2 % NT;
  const int ocb  = r2 / NT;

  if constexpr (MODE == 0) {
    if (tid == 0) { s_sc[0] = 1.f/0.229f; s_sf[0] = -0.485f/0.229f; }
    else if (tid == 1) { s_sc[1] = 1.f/0.224f; s_sf[1] = -0.456f/0.224f; }
    else if (tid == 2) { s_sc[2] = 1.f/0.225f; s_sf[2] = -0.406f/0.225f; }
  } else {
    if (tid < CIN) {
      float S = stat_in[(b*CIN+tid)*2+0], Q = stat_in[(b*CIN+tid)*2+1];
      float mean = S*(1.0f/NPXPREV);
      float var  = Q*(1.0f/NPXPREV) - mean*mean;
      float rstd = rsqrtf(var + 1e-5f);
      float gg = gam[tid], bb = bet[tid];
      s_sc[tid] = gg*rstd;
      s_sf[tid] = bb - mean*gg*rstd;
    }
  }
  __syncthreads();

  const int iy0 = tile*(2*TH) - 1;
  const float* xb_g = xin + (size_t)b*CIN*HIN*WIN;
  for (int e = tid; e < CIN*(2*TH+1)*(WIN+2); e += BLK) {
    int ic  = e / ((2*TH+1)*(WIN+2));
    int rem = e - ic*((2*TH+1)*(WIN+2));
    int rr  = rem / (WIN+2);
    int cc  = rem - rr*(WIN+2);
    int iy = iy0 + rr, ix = cc - 1;
    float v = 0.f;
    if (iy >= 0 && iy < HIN && ix >= 0 && ix < WIN)
      v = s_sc[ic]*xb_g[ic*HIN*WIN + iy*WIN + ix] + s_sf[ic];
    int off = (ix & 1) ? (SEG + ((ix+1) >> 1)) : (ix >> 1);
    xs[ic*XPI + rr*XROW + off] = v;
  }
  __syncthreads();

  const int s  = tid % NSTRIP_B;
  const int g  = tid / NSTRIP_B;
  const int r  = s / (WOUT/PX);
  const int c0 = (s % (WOUT/PX)) * PX;
  const int oc0 = ocb*OCG + g*OCT;

  float acc[OCT][PX];
  #pragma unroll
  for (int k = 0; k < OCT; ++k) {
    float bb = bias[oc0+k];
    #pragma unroll
    for (int j = 0; j < PX; ++j) acc[k][j] = bb;
  }

  float wv[OCT][9];
  #pragma unroll
  for (int k = 0; k < OCT; ++k) {
    const float* wp = wgt + ((size_t)(oc0+k)*CIN)*9;
    #pragma unroll
    for (int t = 0; t < 9; ++t) wv[k][t] = wp[t];
  }

  for (int ic = 0; ic < CIN; ++ic) {
    float wn[OCT][9];
    if (ic + 1 < CIN) {
      #pragma unroll
      for (int k = 0; k < OCT; ++k) {
        const float* wp = wgt + ((size_t)(oc0+k)*CIN + ic + 1)*9;
        #pragma unroll
        for (int t = 0; t < 9; ++t) wn[k][t] = wp[t];
      }
    }
    const float* xb = xs + ic*XPI;
    #pragma unroll
    for (int ky = 0; ky < 3; ++ky) {
      const float* rowp = xb + (2*r+ky)*XROW;
      float eb[PX], ob[PX+1];
      if constexpr (PX == 8) {
        *(float4*)&eb[0] = *(const float4*)(rowp + c0);
        *(float4*)&eb[4] = *(const float4*)(rowp + c0 + 4);
        *(float4*)&ob[0] = *(const float4*)(rowp + SEG + c0);
        *(float4*)&ob[4] = *(const float4*)(rowp + SEG + c0 + 4);
        ob[8] = rowp[SEG + c0 + 8];
      } else if constexpr (PX == 4) {
        *(float4*)&eb[0] = *(const float4*)(rowp + c0);
        *(float4*)&ob[0] = *(const float4*)(rowp + SEG + c0);
        ob[4] = rowp[SEG + c0 + 4];
      } else if constexpr (PX == 2) {
        *(float2*)&eb[0] = *(const float2*)(rowp + c0);
        *(float2*)&ob[0] = *(const float2*)(rowp + SEG + c0);
        ob[2] = rowp[SEG + c0 + 2];
      } else {
        eb[0] = rowp[c0];
        ob[0] = rowp[SEG + c0];
        ob[1] = rowp[SEG + c0 + 1];
      }
      #pragma unroll
      for (int k = 0; k < OCT; ++k) {
        float w0 = wv[k][ky*3], w1 = wv[k][ky*3+1], w2 = wv[k][ky*3+2];
        #pragma unroll
        for (int j = 0; j < PX; ++j)
          acc[k][j] += w0*ob[j] + w1*eb[j] + w2*ob[j+1];
      }
    }
    if (ic + 1 < CIN) {
      #pragma unroll
      for (int k = 0; k < OCT; ++k)
        #pragma unroll
        for (int t = 0; t < 9; ++t) wv[k][t] = wn[k][t];
    }
  }

  const int oy = tile*TH + r;
  if constexpr (MODE != 2) {
    float lsum[OCT], lsq[OCT];
    #pragma unroll
    for (int k = 0; k < OCT; ++k) {
      float ov[PX];
      float ls = 0.f, lq = 0.f;
      #pragma unroll
      for (int j = 0; j < PX; ++j) {
        float a = acc[k][j];
        a = a >= 0.f ? a : 0.2f*a;
        ov[j] = a; ls += a; lq += a*a;
      }
      lsum[k] = ls; lsq[k] = lq;
      float* yp = yout + (((size_t)b*COUT + oc0 + k)*HOUT + oy)*WOUT + c0;
      if constexpr (PX == 8) {
        *(float4*)yp = *(float4*)&ov[0];
        *(float4*)(yp+4) = *(float4*)&ov[4];
      } else if constexpr (PX == 4) {
        *(float4*)yp = *(float4*)&ov[0];
      } else if constexpr (PX == 2) {
        *(float2*)yp = *(float2*)&ov[0];
      } else {
        *yp = ov[0];
      }
    }
    #pragma unroll
    for (int k = 0; k < OCT; ++k) {
      #pragma unroll
      for (int off = R/2; off > 0; off >>= 1) {
        lsum[k] += __shfl_down(lsum[k], off);
        lsq[k]  += __shfl_down(lsq[k],  off);
      }
    }
    if ((tid & (R-1)) == 0) {
      #pragma unroll
      for (int k = 0; k < OCT; ++k) {
        atomicAdd(&stat_out[(b*COUT + oc0 + k)*2 + 0], lsum[k]);
        atomicAdd(&stat_out[(b*COUT + oc0 + k)*2 + 1], lsq[k]);
      }
    }
  } else {
    float a = acc[0][0];
    a = a >= 0.f ? a : 0.2f*a;
    #pragma unroll
    for (int off = R/2; off > 0; off >>= 1) a += __shfl_down(a, off);
    if ((tid & (R-1)) == 0) atomicAdd(&stat_out[b*COUT + oc0], a);
  }
}

// ---------------- classifier head (featsum -> weights) ----------------
__global__ __launch_bounds__(256) void head_kernel(
    const float* __restrict__ featsum, const float* __restrict__ w0, const float* __restrict__ b0,
    const float* __restrict__ w1, const float* __restrict__ b1, float* __restrict__ wout)
{
  __shared__ float sh_h[8*128];
  const int tid = threadIdx.x;
  for (int i = tid; i < 8*128; i += 256) {
    int b = i >> 7, t = i & 127;
    const float* f = featsum + b*128;
    const float* w = w0 + t*128;
    float a = 0.f;
    for (int k = 0; k < 128; ++k) a += f[k]*w[k];
    a = b0[t] + a*(1.0f/64.0f);
    float c = fminf(fmaxf(a + 3.f, 0.f), 6.f);
    sh_h[i] = a * c * (1.f/6.f);
  }
  __syncthreads();
  for (int i = tid; i < 8*20; i += 256) {
    int b = i/20, n = i - b*20;
    const float* h = sh_h + b*128;
    const float* w = w1 + n*128;
    float a = b1[n];
    for (int k = 0; k < 128; ++k) a += h[k]*w[k];
    wout[b*20 + n] = a;
  }
}

// ---------------- T = luts(300x20) @ w_layers(20x1089) ----------------
__global__ __launch_bounds__(256) void tmat_kernel(
    const float* __restrict__ luts, const float* __restrict__ wl, float* __restrict__ T)
{
  int q = blockIdx.x*256 + threadIdx.x;
  int row = blockIdx.y;
  if (q >= 1089) return;
  float a = 0.f;
  #pragma unroll
  for (int w = 0; w < 20; ++w) a += luts[row*20 + w] * wl[w*1089 + q];
  T[row*1089 + q] = a;
}

// ---------------- pass1: compact fp32 LUT, one corner per entry (float4) ----------------
// ch0: d0=ri, q=bi*33+gi | ch1: d0=gi, q=bi*33+ri | ch2: d0=bi, q=gi*33+ri
__global__ __launch_bounds__(256) void lutc_kernel(
    const float* __restrict__ T, const float* __restrict__ wgt,
    const float* __restrict__ slay, float4* __restrict__ lutc)
{
  const int lin = blockIdx.x;
  const int bt = lin & 7;
  const int i = (lin >> 3)*256 + threadIdx.x;
  if (i >= 35937) return;
  int bi = i / 1089, rem = i - bi*1089, gi = rem / 33, ri = rem - gi*33;
  float w[20];
  #pragma unroll
  for (int n = 0; n < 20; ++n) w[n] = wgt[bt*20 + n];

  const int qv[3]  = { bi*33 + gi, bi*33 + ri, gi*33 + ri };
  const int d0v[3] = { ri, gi, bi };
  float outv[3];
  #pragma unroll
  for (int ch = 0; ch < 3; ++ch) {
    float val = 0.f;
    #pragma unroll
    for (int s = 0; s < 5; ++s) {
      float t = 0.f;
      #pragma unroll
      for (int n = 0; n < 20; ++n)
        t += w[n] * T[(s*60 + n*3 + ch)*1089 + qv[ch]];
      val += slay[d0v[ch]*5 + s] * t;
    }
    outv[ch] = val;
  }
  lutc[(size_t)bt*35937 + i] = make_float4(outv[0], outv[1], outv[2], 0.f);
}

// ---------------- pass2: quantized quad table, 16B per (b,g,r) entry ----------------
// entry = 4 corners (g+dg, r+dr), each dword j=dg*2+dr: ch0|ch1<<10|ch2<<20 (10-bit codes)
// plus 2 bits of the shared exponent E in bits 30..31 of each dword.
// code q = round(x * 511 / 2^e) + 512; E = e + 127.
__global__ __launch_bounds__(256) void lutq_kernel(
    const float4* __restrict__ lutc, uint4* __restrict__ lutq)
{
  const int lin = blockIdx.x;
  const int bt = lin & 7;
  const int i = (lin >> 3)*256 + threadIdx.x;
  if (i >= 35937) return;
  int bi = i / 1089, rem = i - bi*1089, gi = rem / 33, ri = rem - gi*33;
  const int g1 = gi < 32 ? gi+1 : 32, r1 = ri < 32 ? ri+1 : 32;
  const float4* base = lutc + (size_t)bt*35937;
  float4 c[4];
  c[0] = base[(bi*33 + gi)*33 + ri];
  c[1] = base[(bi*33 + gi)*33 + r1];
  c[2] = base[(bi*33 + g1)*33 + ri];
  c[3] = base[(bi*33 + g1)*33 + r1];
  float m = 0.f;
  #pragma unroll
  for (int j = 0; j < 4; ++j) {
    m = fmaxf(m, fabsf(c[j].x));
    m = fmaxf(m, fabsf(c[j].y));
    m = fmaxf(m, fabsf(c[j].z));
  }
  int e = 0;
  if (m > 0.f) frexpf(m, &e);           // m = f*2^e, f in [0.5,1) -> |x| < 2^e
  int E = e + 127; E = E < 0 ? 0 : (E > 255 ? 255 : E);
  float sc = ldexpf(511.0f, -e);
  unsigned dw[4];
  #pragma unroll
  for (int j = 0; j < 4; ++j) {
    int q0 = (int)rintf(c[j].x*sc) + 512;
    int q1 = (int)rintf(c[j].y*sc) + 512;
    int q2 = (int)rintf(c[j].z*sc) + 512;
    q0 = q0 < 0 ? 0 : (q0 > 1023 ? 1023 : q0);
    q1 = q1 < 0 ? 0 : (q1 > 1023 ? 1023 : q1);
    q2 = q2 < 0 ? 0 : (q2 > 1023 ? 1023 : q2);
    dw[j] = (unsigned)q0 | ((unsigned)q1 << 10) | ((unsigned)q2 << 20)
          | (((unsigned)(E >> (2*j)) & 3u) << 30);
  }
  lutq[(size_t)bt*35937 + i] = make_uint4(dw[0], dw[1], dw[2], dw[3]);
}

// ---------------- trilinear apply + residual: 2 gathers (16B) per pixel ----------------
__device__ __forceinline__ void quad_accum(uint4 e, float w0, float w1, float w2, float w3,
                                           float wbf, float& rr, float& gg, float& bb)
{
  int E = (int)(e.x >> 30) | (int)((e.y >> 30) << 2)
        | (int)((e.z >> 30) << 4) | (int)((e.w >> 30) << 6);
  float f = ldexpf(1.0f/511.0f, E - 127) * wbf;
  float ar = w0*(float)(e.x & 1023u) + w1*(float)(e.y & 1023u)
           + w2*(float)(e.z & 1023u) + w3*(float)(e.w & 1023u);
  float ag = w0*(float)((e.x >> 10) & 1023u) + w1*(float)((e.y >> 10) & 1023u)
           + w2*(float)((e.z >> 10) & 1023u) + w3*(float)((e.w >> 10) & 1023u);
  float ab = w0*(float)((e.x >> 20) & 1023u) + w1*(float)((e.y >> 20) & 1023u)
           + w2*(float)((e.z >> 20) & 1023u) + w3*(float)((e.w >> 20) & 1023u);
  rr += (ar - 512.f) * f;
  gg += (ag - 512.f) * f;
  bb += (ab - 512.f) * f;
}

__global__ __launch_bounds__(256) void trilin_kernel(
    const float* __restrict__ img, const uint4* __restrict__ lut, float* __restrict__ out)
{
  constexpr int NPX = 720*1280;
  const int lin = blockIdx.x;
  const int bt = lin & 7;
  const int v = (lin >> 3)*256 + threadIdx.x;   // < NPX/4 exactly (900*256)
  const float* ib = img + (size_t)bt*3*NPX;
  float4 r4 = *((const float4*)ib + v);
  float4 g4 = *((const float4*)(ib + NPX) + v);
  float4 b4 = *((const float4*)(ib + 2*NPX) + v);
  const uint4* L = lut + (size_t)bt*35937;
  const float invbin = 32.0f/1.000001f;

  int base[4];
  float fr[4], fg[4], fb[4];
  #pragma unroll
  for (int j = 0; j < 4; ++j) {
    float r = ((float*)&r4)[j], g = ((float*)&g4)[j], b = ((float*)&b4)[j];
    float pr = r*invbin, pg = g*invbin, pb = b*invbin;
    int ri = (int)pr; ri = ri > 31 ? 31 : ri; ri = ri < 0 ? 0 : ri;
    int gi = (int)pg; gi = gi > 31 ? 31 : gi; gi = gi < 0 ? 0 : gi;
    int bi = (int)pb; bi = bi > 31 ? 31 : bi; bi = bi < 0 ? 0 : bi;
    fr[j] = pr - ri; fg[j] = pg - gi; fb[j] = pb - bi;
    base[j] = (bi*33 + gi)*33 + ri;
  }
  uint4 e0[4], e1[4];
  #pragma unroll
  for (int j = 0; j < 4; ++j) {
    e0[j] = L[base[j]];
    e1[j] = L[base[j] + 1089];
  }
  float4 ro, go, bo;
  float* rp = (float*)&ro; float* gp = (float*)&go; float* bp = (float*)&bo;
  #pragma unroll
  for (int j = 0; j < 4; ++j) {
    float wr1 = fr[j], wr0 = 1.f - fr[j];
    float wg1 = fg[j], wg0 = 1.f - fg[j];
    float w0 = wg0*wr0, w1 = wg0*wr1, w2 = wg1*wr0, w3 = wg1*wr1;
    float rr = 0.f, gg = 0.f, bb2 = 0.f;
    quad_accum(e0[j], w0, w1, w2, w3, 1.f - fb[j], rr, gg, bb2);
    quad_accum(e1[j], w0, w1, w2, w3, fb[j],       rr, gg, bb2);
    rp[j] = rr  + ((float*)&r4)[j];
    gp[j] = gg  + ((float*)&g4)[j];
    bp[j] = bb2 + ((float*)&b4)[j];
  }
  float* ob = out + (size_t)bt*3*NPX;
  *((float4*)ob + v) = ro;
  *((float4*)(ob + NPX) + v) = go;
  *((float4*)(ob + 2*NPX) + v) = bo;
}

// ---------------- launcher ----------------
extern "C" void kernel_launch(void* const* d_in, const int* in_sizes, int n_in,
                              void* d_out, int out_size, void* d_ws, size_t ws_size,
                              hipStream_t stream) {
  const float* img     = (const float*)d_in[0];
  const float* img_org = (const float*)d_in[1];
  const float* c0w = (const float*)d_in[2];  const float* c0b = (const float*)d_in[3];
  const float* c1w = (const float*)d_in[4];  const float* c1b = (const float*)d_in[5];
  const float* c2w = (const float*)d_in[6];  const float* c2b = (const float*)d_in[7];
  const float* c3w = (const float*)d_in[8];  const float* c3b = (const float*)d_in[9];
  const float* c4w = (const float*)d_in[10]; const float* c4b = (const float*)d_in[11];
  const float* n0g = (const float*)d_in[12]; const float* n0b = (const float*)d_in[13];
  const float* n1g = (const float*)d_in[14]; const float* n1b = (const float*)d_in[15];
  const float* n2g = (const float*)d_in[16]; const float* n2b = (const float*)d_in[17];
  const float* n3g = (const float*)d_in[18]; const float* n3b = (const float*)d_in[19];
  const float* cls0_w = (const float*)d_in[20]; const float* cls0_b = (const float*)d_in[21];
  const float* cls1_w = (const float*)d_in[22]; const float* cls1_b = (const float*)d_in[23];
  const float* s_layers = (const float*)d_in[24];
  const float* w_layers = (const float*)d_in[25];
  const float* luts     = (const float*)d_in[26];
  float* ws = (float*)d_ws;
  float* out = (float*)d_out;

  // zero stats + featsum
  zero_k<<<19, 256, 0, stream>>>(ws + OFF_STATB, 4864);

  // conv0: 3->16, 256->128. TH=2, OCG=16, PX=8, OCT=2 -> 512 blocks (2/CU)
  conv_tile<3,16,256,256, 2,16, 8,2, 256, 0, 1><<<512, 256, 0, stream>>>(
      img, c0w, c0b, nullptr, nullptr, nullptr, ws + OFF_Y0, ws + OFF_STAT0);
  // conv1: 16->32, 128->64. TH=1, OCG=32, PX=4, OCT=2 -> 512 blocks
  conv_tile<16,32,128,128, 1,32, 4,2, 256, 1, 16384><<<512, 256, 0, stream>>>(
      ws + OFF_Y0, c1w, c1b, ws + OFF_STAT0, n0g, n0b, ws + OFF_Y1, ws + OFF_STAT1);
  // conv2: 32->64, 64->32. TH=1, OCG=32, PX=2, OCT=2 -> 512 blocks
  conv_tile<32,64,64,64, 1,32, 2,2, 256, 1, 4096><<<512, 256, 0, stream>>>(
      ws + OFF_Y1, c2w, c2b, ws + OFF_STAT1, n1g, n1b, ws + OFF_Y2, ws + OFF_STAT2);
  // conv3: 64->128, 32->16. TH=1, OCG=32, PX=2, OCT=1 -> 512 blocks
  conv_tile<64,128,32,32, 1,32, 2,1, 256, 1, 1024><<<512, 256, 0, stream>>>(
      ws + OFF_Y2, c3w, c3b, ws + OFF_STAT2, n2g, n2b, ws + OFF_Y3, ws + OFF_STAT3);
  // conv4: 128->128, 16->8, mean -> featsum (unchanged)
  conv_tile<128,128,16,16, 2,16, 1,1, 256, 2, 256><<<256, 256, 0, stream>>>(
      ws + OFF_Y3, c4w, c4b, ws + OFF_STAT3, n3g, n3b, nullptr, ws + OFF_FEATS);

  head_kernel<<<1, 256, 0, stream>>>(
      ws + OFF_FEATS, cls0_w, cls0_b, cls1_w, cls1_b, ws + OFF_WGT);
  tmat_kernel<<<dim3(5, 300), 256, 0, stream>>>(luts, w_layers, ws + OFF_T);
  lutc_kernel<<<141*8, 256, 0, stream>>>(
      ws + OFF_T, ws + OFF_WGT, s_layers, (float4*)(ws + OFF_LUTCF));
  lutq_kernel<<<141*8, 256, 0, stream>>>(
      (const float4*)(ws + OFF_LUTCF), (uint4*)(ws + OFF_LUTQ));
  trilin_kernel<<<900*8, 256, 0, stream>>>(
      img_org, (const uint4*)(ws + OFF_LUTQ), out);
}